// Round 4
// baseline (274.792 us; speedup 1.0000x reference)
//
#include <hip/hip_runtime.h>
#include <hip/hip_bf16.h>

#define C_DIM 256
#define C8 32
#define N_DIM 4096
#define B_DIM 8
#define SPLIT 4
#define KT_PER 8     // 8 iterations x 128 keys = 1024 keys per split
#define KVBLK 128

using bf16x8 = __attribute__((ext_vector_type(8))) __bf16;
using bf16x4 = __attribute__((ext_vector_type(4))) __bf16;
using f32x4  = __attribute__((ext_vector_type(4))) float;

#define LOG2E 1.44269504088896f
#define SHIFT_L2 17.3123404906675f   // 12 * log2(e)

// ---------------------------------------------------------------------------
// Kernel 0: x[b,c,n] f32  ->  xt[b,n,c] bf16   (LDS tile transpose)
// ---------------------------------------------------------------------------
__global__ __launch_bounds__(256) void k_transpose(
    const float* __restrict__ x, __bf16* __restrict__ xt)
{
    __shared__ float tile[64][65];
    int bid = blockIdx.x;
    int b  = bid >> 8;
    int ct = (bid >> 6) & 3;
    int nt = bid & 63;
    int c0 = ct * 64, n0 = nt * 64;
    int t = threadIdx.x;

    const float* xb = x + (size_t)b * C_DIM * N_DIM;
#pragma unroll
    for (int k = 0; k < 16; k++) {
        int idx = k * 256 + t;
        int i = idx >> 6, j = idx & 63;
        tile[i][j] = xb[(size_t)(c0 + i) * N_DIM + n0 + j];
    }
    __syncthreads();
    __bf16* xtb = xt + (size_t)b * N_DIM * C_DIM;
#pragma unroll
    for (int k = 0; k < 16; k++) {
        int idx = k * 256 + t;
        int nl = idx >> 6, cl = idx & 63;
        xtb[(size_t)(n0 + nl) * C_DIM + c0 + cl] = (__bf16)tile[cl][nl];
    }
}

// ---------------------------------------------------------------------------
// Kernel 1: QKV projection. Q rows are pre-scaled by log2(e) so the attention
// kernel's softmax is a bare exp2(s - shift).
// ---------------------------------------------------------------------------
__global__ __launch_bounds__(256) void k_qkv(
    const float* __restrict__ Wq, const float* __restrict__ bq,
    const float* __restrict__ Wk, const float* __restrict__ bk,
    const float* __restrict__ Wv, const float* __restrict__ bv,
    const __bf16* __restrict__ xt,
    __bf16* __restrict__ Qt, __bf16* __restrict__ Kt, __bf16* __restrict__ Vb)
{
    int bid = blockIdx.x;
    int b   = bid / 320;
    int rem = bid % 320;
    int dt  = rem / 64;
    int nt  = rem % 64;
    int n0  = nt * 64;
    int wid  = threadIdx.x >> 6;
    int lane = threadIdx.x & 63;
    int lg = lane >> 4, li = lane & 15;
    int d0w = dt * 64 + wid * 16;

    int drow = d0w + li;
    const float* wrow;
    if (drow < 32)        wrow = Wq + drow * C_DIM;
    else if (drow < 64)   wrow = Wk + (drow - 32) * C_DIM;
    else                  wrow = Wv + (drow - 64) * C_DIM;

    const __bf16* xtb = xt + (size_t)b * N_DIM * C_DIM;

    f32x4 acc[4] = {};
#pragma unroll
    for (int ks = 0; ks < 8; ks++) {
        int c0 = ks * 32 + lg * 8;
        float4 w0 = *(const float4*)(wrow + c0);
        float4 w1 = *(const float4*)(wrow + c0 + 4);
        bf16x8 af;
        af[0] = (__bf16)w0.x; af[1] = (__bf16)w0.y;
        af[2] = (__bf16)w0.z; af[3] = (__bf16)w0.w;
        af[4] = (__bf16)w1.x; af[5] = (__bf16)w1.y;
        af[6] = (__bf16)w1.z; af[7] = (__bf16)w1.w;
#pragma unroll
        for (int ns = 0; ns < 4; ns++) {
            bf16x8 bfr = *(const bf16x8*)(xtb + (size_t)(n0 + ns * 16 + li) * C_DIM + ks * 32 + lg * 8);
            acc[ns] = __builtin_amdgcn_mfma_f32_16x16x32_bf16(af, bfr, acc[ns], 0, 0, 0);
        }
    }
#pragma unroll
    for (int r = 0; r < 4; r++) {
        int d = d0w + lg * 4 + r;
        float bias = (d < 32) ? bq[d] : (d < 64) ? bk[d - 32] : bv[d - 64];
#pragma unroll
        for (int ns = 0; ns < 4; ns++) {
            int n = n0 + ns * 16 + li;
            float v = acc[ns][r] + bias;
            if (d < 32)
                Qt[((size_t)b * N_DIM + n) * C8 + d] = (__bf16)(v * LOG2E);
            else if (d < 64)
                Kt[((size_t)b * N_DIM + n) * C8 + (d - 32)] = (__bf16)v;
            else
                Vb[((size_t)b * C_DIM + (d - 64)) * N_DIM + n] = (__bf16)v;
        }
    }
}

// ---------------------------------------------------------------------------
// Kernel 2: split-K flash attention, no-max softmax, KVBLK=128.
// Per iteration: issue 16 V loads early (land under QK/exp/barrier),
// 8 QK MFMA, prefetch next K frags, exp2 -> swizzled LDS, 1 barrier,
// PV = 64 MFMA under setprio(1).
// ---------------------------------------------------------------------------
__global__ __launch_bounds__(256, 2) void k_attn(
    const __bf16* __restrict__ Qt, const __bf16* __restrict__ Kt,
    const __bf16* __restrict__ Vb,
    __bf16* __restrict__ Op, float* __restrict__ Ll)
{
    __shared__ __align__(16) __bf16 P_lds[2][4][16][KVBLK];  // 32 KiB

    int bid = blockIdx.x;
    int b  = bid & 7;             // batch == XCD slot (bid%8 dispatch round-robin)
    int qt = (bid >> 3) & 63;
    int sp = bid >> 9;            // key split 0..3
    int n0 = qt * 64;
    int wid  = threadIdx.x >> 6;
    int lane = threadIdx.x & 63;
    int lg = lane >> 4, li = lane & 15;

    const __bf16* Qb  = Qt + (size_t)b * N_DIM * C8;
    const __bf16* Kb  = Kt + (size_t)b * N_DIM * C8;
    const __bf16* Vbb = Vb + (size_t)b * C_DIM * N_DIM;

    bf16x8 qf = *(const bf16x8*)(Qb + (size_t)(n0 + wid * 16 + li) * C8 + lg * 8);

    f32x4 acc[4][4] = {};                 // [ct][np] : 64 ch x 64 queries
    float l_part[4] = {0.f, 0.f, 0.f, 0.f};

    // prefetch K frags for first tile
    int m0_first = sp * KT_PER * KVBLK;
    bf16x8 kf[8];
#pragma unroll
    for (int t = 0; t < 8; t++)
        kf[t] = *(const bf16x8*)(Kb + (size_t)(m0_first + t * 16 + li) * C8 + lg * 8);

    for (int ktl = 0; ktl < KT_PER; ktl++) {
        int m0  = (sp * KT_PER + ktl) * KVBLK;
        int buf = ktl & 1;

        // ---- issue ALL V loads for this iteration now (consumed after barrier)
        bf16x8 vf[16];
#pragma unroll
        for (int kk = 0; kk < 4; kk++)
#pragma unroll
            for (int ct = 0; ct < 4; ct++)
                vf[kk * 4 + ct] = *(const bf16x8*)(Vbb
                    + (size_t)(wid * 64 + ct * 16 + li) * N_DIM + m0 + kk * 32 + lg * 8);

        // ---- S = Q K^T  (16 queries x 128 keys)
        f32x4 s[8];
#pragma unroll
        for (int t = 0; t < 8; t++) {
            f32x4 z = {};
            s[t] = __builtin_amdgcn_mfma_f32_16x16x32_bf16(qf, kf[t], z, 0, 0, 0);
        }

        // ---- prefetch next tile's K frags
        int ktn = (ktl < KT_PER - 1) ? ktl + 1 : ktl;
        int m0n = (sp * KT_PER + ktn) * KVBLK;
#pragma unroll
        for (int t = 0; t < 8; t++)
            kf[t] = *(const bf16x8*)(Kb + (size_t)(m0n + t * 16 + li) * C8 + lg * 8);

        // ---- P = exp2(S - shift) -> bf16 -> swizzled LDS; per-lane partials
        char* pbase = (char*)&P_lds[buf][wid][0][0];
#pragma unroll
        for (int r = 0; r < 4; r++) {
            float lp = 0.f;
            int row = lg * 4 + r;
            int swz = (row & 7) << 4;
#pragma unroll
            for (int t = 0; t < 8; t++) {
                float p = __builtin_amdgcn_exp2f(s[t][r] - SHIFT_L2);
                lp += p;
                int colb = (t * 16 + li) * 2;
                *(__bf16*)(pbase + row * (KVBLK * 2) + (colb ^ swz)) = (__bf16)p;
            }
            l_part[r] += lp;
        }
        __syncthreads();

        // ---- PV: D[c][n] += V[c, m-chunk] * P^T[m-chunk, n]
        __builtin_amdgcn_s_setprio(1);
#pragma unroll
        for (int kk = 0; kk < 4; kk++) {
            bf16x8 pf[4];
#pragma unroll
            for (int np = 0; np < 4; np++) {
                int row = li;
                int colb = kk * 64 + lg * 16;
                pf[np] = *(const bf16x8*)((const char*)&P_lds[buf][np][0][0]
                                          + row * (KVBLK * 2) + (colb ^ ((row & 7) << 4)));
            }
#pragma unroll
            for (int ct = 0; ct < 4; ct++) {
#pragma unroll
                for (int np = 0; np < 4; np++) {
                    acc[ct][np] = __builtin_amdgcn_mfma_f32_16x16x32_bf16(vf[kk * 4 + ct], pf[np], acc[ct][np], 0, 0, 0);
                }
            }
        }
        __builtin_amdgcn_s_setprio(0);
    }

    // ---- epilogue: reduce l over the 16 li lanes (once), write partials
    size_t sb = (size_t)(sp * B_DIM + b);
#pragma unroll
    for (int r = 0; r < 4; r++) {
        float v = l_part[r];
        v += __shfl_xor(v, 1);
        v += __shfl_xor(v, 2);
        v += __shfl_xor(v, 4);
        v += __shfl_xor(v, 8);
        if (li == 0) {
            int q = n0 + wid * 16 + lg * 4 + r;
            Ll[sb * N_DIM + q] = v;
        }
    }
#pragma unroll
    for (int np = 0; np < 4; np++) {
#pragma unroll
        for (int ct = 0; ct < 4; ct++) {
#pragma unroll
            for (int r = 0; r < 4; r++) {
                int c = wid * 64 + ct * 16 + lg * 4 + r;
                int n = n0 + np * 16 + li;
                Op[(sb * C_DIM + c) * N_DIM + n] = (__bf16)acc[ct][np][r];
            }
        }
    }
}

// ---------------------------------------------------------------------------
// Kernel 3: combine (sum partials, one gamma/L multiply, residual)
// ---------------------------------------------------------------------------
__global__ __launch_bounds__(256) void k_combine(
    const float* __restrict__ x, const __bf16* __restrict__ Op,
    const float* __restrict__ Ll,
    const float* __restrict__ gamma, float* __restrict__ out)
{
    int tid = blockIdx.x * 256 + threadIdx.x;   // 131072 total
    int n4 = tid & 1023;
    int cg = (tid >> 10) & 15;
    int b  = tid >> 14;
    int n  = n4 * 4;
    float g = gamma[0];

    float inv[4];
    {
        float L[4] = {0.f, 0.f, 0.f, 0.f};
#pragma unroll
        for (int s = 0; s < SPLIT; s++) {
            float4 t1 = *(const float4*)(Ll + ((size_t)(s * B_DIM + b) << 12) + n);
            L[0] += t1.x; L[1] += t1.y; L[2] += t1.z; L[3] += t1.w;
        }
#pragma unroll
        for (int j = 0; j < 4; j++) inv[j] = g / L[j];
    }

#pragma unroll 4
    for (int ci = 0; ci < 16; ci++) {
        int c = cg * 16 + ci;
        size_t base = (((size_t)b * C_DIM + c) << 12) + n;
        float4 xv = *(const float4*)(x + base);
        float o0 = 0.f, o1 = 0.f, o2 = 0.f, o3 = 0.f;
#pragma unroll
        for (int s = 0; s < SPLIT; s++) {
            bf16x4 p = *(const bf16x4*)(Op + (((size_t)(s * B_DIM + b) * C_DIM + c) << 12) + n);
            o0 += (float)p[0];
            o1 += (float)p[1];
            o2 += (float)p[2];
            o3 += (float)p[3];
        }
        float4 ov = { xv.x + o0 * inv[0], xv.y + o1 * inv[1],
                      xv.z + o2 * inv[2], xv.w + o3 * inv[3] };
        *(float4*)(out + base) = ov;
    }
}

// ---------------------------------------------------------------------------
extern "C" void kernel_launch(void* const* d_in, const int* in_sizes, int n_in,
                              void* d_out, int out_size, void* d_ws, size_t ws_size,
                              hipStream_t stream)
{
    const float* x     = (const float*)d_in[0];
    const float* Wq    = (const float*)d_in[1];
    const float* bq    = (const float*)d_in[2];
    const float* Wk    = (const float*)d_in[3];
    const float* bk    = (const float*)d_in[4];
    const float* Wv    = (const float*)d_in[5];
    const float* bv    = (const float*)d_in[6];
    const float* gamma = (const float*)d_in[7];
    float* out = (float*)d_out;

    char* ws = (char*)d_ws;
    const size_t MB = 1024 * 1024;
    __bf16* xt = (__bf16*)ws;                      // 16 MiB
    __bf16* Qt = (__bf16*)(ws + 16 * MB);          //  2 MiB
    __bf16* Kt = (__bf16*)(ws + 18 * MB);          //  2 MiB
    __bf16* Vb = (__bf16*)(ws + 20 * MB);          // 16 MiB
    __bf16* Op = (__bf16*)(ws + 36 * MB);          // 64 MiB (4 splits x 32MB bf16)
    float*  Ll = (float*)(ws + 100 * MB);          // 512 KiB

    k_transpose<<<2048, 256, 0, stream>>>(x, xt);
    k_qkv<<<2560, 256, 0, stream>>>(Wq, bq, Wk, bk, Wv, bv, xt, Qt, Kt, Vb);
    k_attn<<<512 * SPLIT, 256, 0, stream>>>(Qt, Kt, Vb, Op, Ll);
    k_combine<<<512, 256, 0, stream>>>(x, Op, Ll, gamma, out);
}

// Round 5
// 246.311 us; speedup vs baseline: 1.1156x; 1.1156x over previous
//
#include <hip/hip_runtime.h>
#include <hip/hip_bf16.h>

#define C_DIM 256
#define C8 32
#define N_DIM 4096
#define B_DIM 8
#define SPLIT 4
#define KT_PER 16   // 16 iterations x 64 keys = 1024 keys per split
#define KVBLK 64

using bf16x8 = __attribute__((ext_vector_type(8))) __bf16;
using bf16x4 = __attribute__((ext_vector_type(4))) __bf16;
using f32x4  = __attribute__((ext_vector_type(4))) float;

#define LOG2E 1.44269504088896f
#define SHIFT_L2 17.3123404906675f   // 12 * log2(e)

// ---------------------------------------------------------------------------
// Kernel 0: x[b,c,n] f32  ->  xt[b,n,c] bf16   (LDS tile transpose)
// ---------------------------------------------------------------------------
__global__ __launch_bounds__(256) void k_transpose(
    const float* __restrict__ x, __bf16* __restrict__ xt)
{
    __shared__ float tile[64][65];
    int bid = blockIdx.x;
    int b  = bid >> 8;
    int ct = (bid >> 6) & 3;
    int nt = bid & 63;
    int c0 = ct * 64, n0 = nt * 64;
    int t = threadIdx.x;

    const float* xb = x + (size_t)b * C_DIM * N_DIM;
#pragma unroll
    for (int k = 0; k < 16; k++) {
        int idx = k * 256 + t;
        int i = idx >> 6, j = idx & 63;
        tile[i][j] = xb[(size_t)(c0 + i) * N_DIM + n0 + j];
    }
    __syncthreads();
    __bf16* xtb = xt + (size_t)b * N_DIM * C_DIM;
#pragma unroll
    for (int k = 0; k < 16; k++) {
        int idx = k * 256 + t;
        int nl = idx >> 6, cl = idx & 63;
        xtb[(size_t)(n0 + nl) * C_DIM + c0 + cl] = (__bf16)tile[cl][nl];
    }
}

// ---------------------------------------------------------------------------
// Kernel 1: QKV projection. Q rows pre-scaled by log2(e) -> attn softmax is a
// bare exp2(s - shift).
// ---------------------------------------------------------------------------
__global__ __launch_bounds__(256) void k_qkv(
    const float* __restrict__ Wq, const float* __restrict__ bq,
    const float* __restrict__ Wk, const float* __restrict__ bk,
    const float* __restrict__ Wv, const float* __restrict__ bv,
    const __bf16* __restrict__ xt,
    __bf16* __restrict__ Qt, __bf16* __restrict__ Kt, __bf16* __restrict__ Vb)
{
    int bid = blockIdx.x;
    int b   = bid / 320;
    int rem = bid % 320;
    int dt  = rem / 64;
    int nt  = rem % 64;
    int n0  = nt * 64;
    int wid  = threadIdx.x >> 6;
    int lane = threadIdx.x & 63;
    int lg = lane >> 4, li = lane & 15;
    int d0w = dt * 64 + wid * 16;

    int drow = d0w + li;
    const float* wrow;
    if (drow < 32)        wrow = Wq + drow * C_DIM;
    else if (drow < 64)   wrow = Wk + (drow - 32) * C_DIM;
    else                  wrow = Wv + (drow - 64) * C_DIM;

    const __bf16* xtb = xt + (size_t)b * N_DIM * C_DIM;

    f32x4 acc[4] = {};
#pragma unroll
    for (int ks = 0; ks < 8; ks++) {
        int c0 = ks * 32 + lg * 8;
        float4 w0 = *(const float4*)(wrow + c0);
        float4 w1 = *(const float4*)(wrow + c0 + 4);
        bf16x8 af;
        af[0] = (__bf16)w0.x; af[1] = (__bf16)w0.y;
        af[2] = (__bf16)w0.z; af[3] = (__bf16)w0.w;
        af[4] = (__bf16)w1.x; af[5] = (__bf16)w1.y;
        af[6] = (__bf16)w1.z; af[7] = (__bf16)w1.w;
#pragma unroll
        for (int ns = 0; ns < 4; ns++) {
            bf16x8 bfr = *(const bf16x8*)(xtb + (size_t)(n0 + ns * 16 + li) * C_DIM + ks * 32 + lg * 8);
            acc[ns] = __builtin_amdgcn_mfma_f32_16x16x32_bf16(af, bfr, acc[ns], 0, 0, 0);
        }
    }
#pragma unroll
    for (int r = 0; r < 4; r++) {
        int d = d0w + lg * 4 + r;
        float bias = (d < 32) ? bq[d] : (d < 64) ? bk[d - 32] : bv[d - 64];
#pragma unroll
        for (int ns = 0; ns < 4; ns++) {
            int n = n0 + ns * 16 + li;
            float v = acc[ns][r] + bias;
            if (d < 32)
                Qt[((size_t)b * N_DIM + n) * C8 + d] = (__bf16)(v * LOG2E);
            else if (d < 64)
                Kt[((size_t)b * N_DIM + n) * C8 + (d - 32)] = (__bf16)v;
            else
                Vb[((size_t)b * C_DIM + (d - 64)) * N_DIM + n] = (__bf16)v;
        }
    }
}

// ---------------------------------------------------------------------------
// Kernel 2: split-K flash attention, no-max softmax, KVBLK=64 (R3 shape).
// Register-budgeted pipeline:
//   - kf[4] prefetched one iteration ahead (16 VGPR)
//   - vf0[4] (kk=0 V frags) issued BEFORE the barrier -> L2 latency lands
//     under exp/ds_write/barrier instead of heading the PV critical path
//   - kk=1 V frags issued at PV start, hidden under kk=0's 16 MFMAs
//   - setprio(1) around the PV MFMA cluster
// ---------------------------------------------------------------------------
__global__ __launch_bounds__(256, 3) void k_attn(
    const __bf16* __restrict__ Qt, const __bf16* __restrict__ Kt,
    const __bf16* __restrict__ Vb,
    __bf16* __restrict__ Op, float* __restrict__ Ll)
{
    __shared__ __align__(16) __bf16 P_lds[2][4][16][KVBLK];  // 16 KiB

    int bid = blockIdx.x;
    int b  = bid & 7;             // batch == XCD slot (bid%8 dispatch round-robin)
    int qt = (bid >> 3) & 63;
    int sp = bid >> 9;            // key split 0..3
    int n0 = qt * 64;
    int wid  = threadIdx.x >> 6;
    int lane = threadIdx.x & 63;
    int lg = lane >> 4, li = lane & 15;

    const __bf16* Qb  = Qt + (size_t)b * N_DIM * C8;
    const __bf16* Kb  = Kt + (size_t)b * N_DIM * C8;
    const __bf16* Vbb = Vb + (size_t)b * C_DIM * N_DIM;

    bf16x8 qf = *(const bf16x8*)(Qb + (size_t)(n0 + wid * 16 + li) * C8 + lg * 8);

    f32x4 acc[4][4] = {};                 // [ct][np] : 64 ch x 64 queries
    float l_part[4] = {0.f, 0.f, 0.f, 0.f};

    // prefetch K frags for first tile
    int m0_first = sp * KT_PER * KVBLK;
    bf16x8 kf[4];
#pragma unroll
    for (int t = 0; t < 4; t++)
        kf[t] = *(const bf16x8*)(Kb + (size_t)(m0_first + t * 16 + li) * C8 + lg * 8);

    for (int ktl = 0; ktl < KT_PER; ktl++) {
        int m0  = (sp * KT_PER + ktl) * KVBLK;
        int buf = ktl & 1;

        // ---- S = Q K^T  (16 queries x 64 keys)
        f32x4 s[4];
#pragma unroll
        for (int t = 0; t < 4; t++) {
            f32x4 z = {};
            s[t] = __builtin_amdgcn_mfma_f32_16x16x32_bf16(qf, kf[t], z, 0, 0, 0);
        }

        // ---- issue kk=0 V frags now: consumed after the barrier
        bf16x8 vf0[4];
#pragma unroll
        for (int ct = 0; ct < 4; ct++)
            vf0[ct] = *(const bf16x8*)(Vbb
                + (size_t)(wid * 64 + ct * 16 + li) * N_DIM + m0 + lg * 8);

        // ---- prefetch next tile's K frags
        int ktn = (ktl < KT_PER - 1) ? ktl + 1 : ktl;
        int m0n = (sp * KT_PER + ktn) * KVBLK;
#pragma unroll
        for (int t = 0; t < 4; t++)
            kf[t] = *(const bf16x8*)(Kb + (size_t)(m0n + t * 16 + li) * C8 + lg * 8);

        // ---- P = exp2(S - shift) -> bf16 -> swizzled LDS; per-lane partials
        char* pbase = (char*)&P_lds[buf][wid][0][0];
#pragma unroll
        for (int r = 0; r < 4; r++) {
            float lp = 0.f;
            int row = lg * 4 + r;
            int swz = (row & 7) << 4;
#pragma unroll
            for (int t = 0; t < 4; t++) {
                float p = __builtin_amdgcn_exp2f(s[t][r] - SHIFT_L2);
                lp += p;
                int colb = (t * 16 + li) * 2;
                *(__bf16*)(pbase + row * (KVBLK * 2) + (colb ^ swz)) = (__bf16)p;
            }
            l_part[r] += lp;
        }
        __syncthreads();

        // ---- PV: D[c][n] += V[c, m-chunk] * P^T[m-chunk, n]
        // kk=0 uses pre-issued vf0; kk=1 frags issue here, hidden under kk=0 MFMAs
        bf16x8 vf1[4];
#pragma unroll
        for (int ct = 0; ct < 4; ct++)
            vf1[ct] = *(const bf16x8*)(Vbb
                + (size_t)(wid * 64 + ct * 16 + li) * N_DIM + m0 + 32 + lg * 8);

        __builtin_amdgcn_s_setprio(1);
        {
            bf16x8 pf[4];
#pragma unroll
            for (int np = 0; np < 4; np++) {
                int row = li;
                int colb = lg * 16;
                pf[np] = *(const bf16x8*)((const char*)&P_lds[buf][np][0][0]
                                          + row * (KVBLK * 2) + (colb ^ ((row & 7) << 4)));
            }
#pragma unroll
            for (int ct = 0; ct < 4; ct++)
#pragma unroll
                for (int np = 0; np < 4; np++)
                    acc[ct][np] = __builtin_amdgcn_mfma_f32_16x16x32_bf16(vf0[ct], pf[np], acc[ct][np], 0, 0, 0);
        }
        {
            bf16x8 pf[4];
#pragma unroll
            for (int np = 0; np < 4; np++) {
                int row = li;
                int colb = 64 + lg * 16;
                pf[np] = *(const bf16x8*)((const char*)&P_lds[buf][np][0][0]
                                          + row * (KVBLK * 2) + (colb ^ ((row & 7) << 4)));
            }
#pragma unroll
            for (int ct = 0; ct < 4; ct++)
#pragma unroll
                for (int np = 0; np < 4; np++)
                    acc[ct][np] = __builtin_amdgcn_mfma_f32_16x16x32_bf16(vf1[ct], pf[np], acc[ct][np], 0, 0, 0);
        }
        __builtin_amdgcn_s_setprio(0);
    }

    // ---- epilogue: reduce l over the 16 li lanes (once), write partials
    size_t sb = (size_t)(sp * B_DIM + b);
#pragma unroll
    for (int r = 0; r < 4; r++) {
        float v = l_part[r];
        v += __shfl_xor(v, 1);
        v += __shfl_xor(v, 2);
        v += __shfl_xor(v, 4);
        v += __shfl_xor(v, 8);
        if (li == 0) {
            int q = n0 + wid * 16 + lg * 4 + r;
            Ll[sb * N_DIM + q] = v;
        }
    }
#pragma unroll
    for (int np = 0; np < 4; np++) {
#pragma unroll
        for (int ct = 0; ct < 4; ct++) {
#pragma unroll
            for (int r = 0; r < 4; r++) {
                int c = wid * 64 + ct * 16 + lg * 4 + r;
                int n = n0 + np * 16 + li;
                Op[(sb * C_DIM + c) * N_DIM + n] = (__bf16)acc[ct][np][r];
            }
        }
    }
}

// ---------------------------------------------------------------------------
// Kernel 3: combine (sum partials, one gamma/L multiply, residual)
// ---------------------------------------------------------------------------
__global__ __launch_bounds__(256) void k_combine(
    const float* __restrict__ x, const __bf16* __restrict__ Op,
    const float* __restrict__ Ll,
    const float* __restrict__ gamma, float* __restrict__ out)
{
    int tid = blockIdx.x * 256 + threadIdx.x;   // 131072 total
    int n4 = tid & 1023;
    int cg = (tid >> 10) & 15;
    int b  = tid >> 14;
    int n  = n4 * 4;
    float g = gamma[0];

    float inv[4];
    {
        float L[4] = {0.f, 0.f, 0.f, 0.f};
#pragma unroll
        for (int s = 0; s < SPLIT; s++) {
            float4 t1 = *(const float4*)(Ll + ((size_t)(s * B_DIM + b) << 12) + n);
            L[0] += t1.x; L[1] += t1.y; L[2] += t1.z; L[3] += t1.w;
        }
#pragma unroll
        for (int j = 0; j < 4; j++) inv[j] = g / L[j];
    }

#pragma unroll 4
    for (int ci = 0; ci < 16; ci++) {
        int c = cg * 16 + ci;
        size_t base = (((size_t)b * C_DIM + c) << 12) + n;
        float4 xv = *(const float4*)(x + base);
        float o0 = 0.f, o1 = 0.f, o2 = 0.f, o3 = 0.f;
#pragma unroll
        for (int s = 0; s < SPLIT; s++) {
            bf16x4 p = *(const bf16x4*)(Op + (((size_t)(s * B_DIM + b) * C_DIM + c) << 12) + n);
            o0 += (float)p[0];
            o1 += (float)p[1];
            o2 += (float)p[2];
            o3 += (float)p[3];
        }
        float4 ov = { xv.x + o0 * inv[0], xv.y + o1 * inv[1],
                      xv.z + o2 * inv[2], xv.w + o3 * inv[3] };
        *(float4*)(out + base) = ov;
    }
}

// ---------------------------------------------------------------------------
extern "C" void kernel_launch(void* const* d_in, const int* in_sizes, int n_in,
                              void* d_out, int out_size, void* d_ws, size_t ws_size,
                              hipStream_t stream)
{
    const float* x     = (const float*)d_in[0];
    const float* Wq    = (const float*)d_in[1];
    const float* bq    = (const float*)d_in[2];
    const float* Wk    = (const float*)d_in[3];
    const float* bk    = (const float*)d_in[4];
    const float* Wv    = (const float*)d_in[5];
    const float* bv    = (const float*)d_in[6];
    const float* gamma = (const float*)d_in[7];
    float* out = (float*)d_out;

    char* ws = (char*)d_ws;
    const size_t MB = 1024 * 1024;
    __bf16* xt = (__bf16*)ws;                      // 16 MiB
    __bf16* Qt = (__bf16*)(ws + 16 * MB);          //  2 MiB
    __bf16* Kt = (__bf16*)(ws + 18 * MB);          //  2 MiB
    __bf16* Vb = (__bf16*)(ws + 20 * MB);          // 16 MiB
    __bf16* Op = (__bf16*)(ws + 36 * MB);          // 64 MiB (4 splits x 32MB bf16)
    float*  Ll = (float*)(ws + 100 * MB);          // 512 KiB

    k_transpose<<<2048, 256, 0, stream>>>(x, xt);
    k_qkv<<<2560, 256, 0, stream>>>(Wq, bq, Wk, bk, Wv, bv, xt, Qt, Kt, Vb);
    k_attn<<<512 * SPLIT, 256, 0, stream>>>(Qt, Kt, Vb, Op, Ll);
    k_combine<<<512, 256, 0, stream>>>(x, Op, Ll, gamma, out);
}

// Round 6
// 246.265 us; speedup vs baseline: 1.1158x; 1.0002x over previous
//
#include <hip/hip_runtime.h>
#include <hip/hip_bf16.h>

#define C_DIM 256
#define C8 32
#define N_DIM 4096
#define B_DIM 8
#define SPLIT 2
#define KT_PER 32   // 32 iterations x 64 keys = 2048 keys per split
#define KVBLK 64

using bf16x8 = __attribute__((ext_vector_type(8))) __bf16;
using bf16x4 = __attribute__((ext_vector_type(4))) __bf16;
using f32x4  = __attribute__((ext_vector_type(4))) float;

#define LOG2E 1.44269504088896f
#define SHIFT_L2 17.3123404906675f   // 12 * log2(e)

// ---------------------------------------------------------------------------
// Kernel 0: x[b,c,n] f32  ->  xt[b,n,c] bf16   (LDS tile transpose)
// ---------------------------------------------------------------------------
__global__ __launch_bounds__(256) void k_transpose(
    const float* __restrict__ x, __bf16* __restrict__ xt)
{
    __shared__ float tile[64][65];
    int bid = blockIdx.x;
    int b  = bid >> 8;
    int ct = (bid >> 6) & 3;
    int nt = bid & 63;
    int c0 = ct * 64, n0 = nt * 64;
    int t = threadIdx.x;

    const float* xb = x + (size_t)b * C_DIM * N_DIM;
#pragma unroll
    for (int k = 0; k < 16; k++) {
        int idx = k * 256 + t;
        int i = idx >> 6, j = idx & 63;
        tile[i][j] = xb[(size_t)(c0 + i) * N_DIM + n0 + j];
    }
    __syncthreads();
    __bf16* xtb = xt + (size_t)b * N_DIM * C_DIM;
#pragma unroll
    for (int k = 0; k < 16; k++) {
        int idx = k * 256 + t;
        int nl = idx >> 6, cl = idx & 63;
        xtb[(size_t)(n0 + nl) * C_DIM + c0 + cl] = (__bf16)tile[cl][nl];
    }
}

// ---------------------------------------------------------------------------
// Kernel 1: QKV projection. Q rows pre-scaled by log2(e) -> attn softmax is a
// bare exp2(s - shift).
// ---------------------------------------------------------------------------
__global__ __launch_bounds__(256) void k_qkv(
    const float* __restrict__ Wq, const float* __restrict__ bq,
    const float* __restrict__ Wk, const float* __restrict__ bk,
    const float* __restrict__ Wv, const float* __restrict__ bv,
    const __bf16* __restrict__ xt,
    __bf16* __restrict__ Qt, __bf16* __restrict__ Kt, __bf16* __restrict__ Vb)
{
    int bid = blockIdx.x;
    int b   = bid / 320;
    int rem = bid % 320;
    int dt  = rem / 64;
    int nt  = rem % 64;
    int n0  = nt * 64;
    int wid  = threadIdx.x >> 6;
    int lane = threadIdx.x & 63;
    int lg = lane >> 4, li = lane & 15;
    int d0w = dt * 64 + wid * 16;

    int drow = d0w + li;
    const float* wrow;
    if (drow < 32)        wrow = Wq + drow * C_DIM;
    else if (drow < 64)   wrow = Wk + (drow - 32) * C_DIM;
    else                  wrow = Wv + (drow - 64) * C_DIM;

    const __bf16* xtb = xt + (size_t)b * N_DIM * C_DIM;

    f32x4 acc[4] = {};
#pragma unroll
    for (int ks = 0; ks < 8; ks++) {
        int c0 = ks * 32 + lg * 8;
        float4 w0 = *(const float4*)(wrow + c0);
        float4 w1 = *(const float4*)(wrow + c0 + 4);
        bf16x8 af;
        af[0] = (__bf16)w0.x; af[1] = (__bf16)w0.y;
        af[2] = (__bf16)w0.z; af[3] = (__bf16)w0.w;
        af[4] = (__bf16)w1.x; af[5] = (__bf16)w1.y;
        af[6] = (__bf16)w1.z; af[7] = (__bf16)w1.w;
#pragma unroll
        for (int ns = 0; ns < 4; ns++) {
            bf16x8 bfr = *(const bf16x8*)(xtb + (size_t)(n0 + ns * 16 + li) * C_DIM + ks * 32 + lg * 8);
            acc[ns] = __builtin_amdgcn_mfma_f32_16x16x32_bf16(af, bfr, acc[ns], 0, 0, 0);
        }
    }
#pragma unroll
    for (int r = 0; r < 4; r++) {
        int d = d0w + lg * 4 + r;
        float bias = (d < 32) ? bq[d] : (d < 64) ? bk[d - 32] : bv[d - 64];
#pragma unroll
        for (int ns = 0; ns < 4; ns++) {
            int n = n0 + ns * 16 + li;
            float v = acc[ns][r] + bias;
            if (d < 32)
                Qt[((size_t)b * N_DIM + n) * C8 + d] = (__bf16)(v * LOG2E);
            else if (d < 64)
                Kt[((size_t)b * N_DIM + n) * C8 + (d - 32)] = (__bf16)v;
            else
                Vb[((size_t)b * C_DIM + (d - 64)) * N_DIM + n] = (__bf16)v;
        }
    }
}

// ---------------------------------------------------------------------------
// Kernel 2: split-K flash attention, no-max softmax, cross-iteration pipeline.
// Triple-buffered P_lds; iteration i computes exp(tile i+1) ADJACENT to
// PV(tile i) — independent regions, so exp's VALU chain hides under the PV
// MFMA cluster. One barrier per iteration (3 buffers => writer is 2 barriers
// from the last reader). Register budget: vf1 issued inside PV (short-lived);
// vf0 + kf + s live across the exp region.
// ---------------------------------------------------------------------------
__global__ __launch_bounds__(256, 3) void k_attn(
    const __bf16* __restrict__ Qt, const __bf16* __restrict__ Kt,
    const __bf16* __restrict__ Vb,
    __bf16* __restrict__ Op, float* __restrict__ Ll)
{
    __shared__ __align__(16) __bf16 P_lds[3][4][16][KVBLK];  // 24 KiB

    int bid = blockIdx.x;
    int b  = bid & 7;             // batch == XCD slot (bid%8 dispatch round-robin)
    int qt = (bid >> 3) & 63;
    int sp = bid >> 9;            // key split 0..1
    int n0 = qt * 64;
    int wid  = threadIdx.x >> 6;
    int lane = threadIdx.x & 63;
    int lg = lane >> 4, li = lane & 15;

    const __bf16* Qb  = Qt + (size_t)b * N_DIM * C8;
    const __bf16* Kb  = Kt + (size_t)b * N_DIM * C8;
    const __bf16* Vbb = Vb + (size_t)b * C_DIM * N_DIM;

    bf16x8 qf = *(const bf16x8*)(Qb + (size_t)(n0 + wid * 16 + li) * C8 + lg * 8);

    f32x4 acc[4][4] = {};                 // [ct][np] : 64 ch x 64 queries
    float l_part[4] = {0.f, 0.f, 0.f, 0.f};

    int base_kt = sp * KT_PER;

    // ---- prologue: K0 -> S0 -> exp -> P[0]; prefetch K1
    bf16x8 kf[4];
#pragma unroll
    for (int t = 0; t < 4; t++)
        kf[t] = *(const bf16x8*)(Kb + (size_t)(base_kt * KVBLK + t * 16 + li) * C8 + lg * 8);

    {
        f32x4 s[4];
#pragma unroll
        for (int t = 0; t < 4; t++) {
            f32x4 z = {};
            s[t] = __builtin_amdgcn_mfma_f32_16x16x32_bf16(qf, kf[t], z, 0, 0, 0);
        }
#pragma unroll
        for (int t = 0; t < 4; t++)
            kf[t] = *(const bf16x8*)(Kb + (size_t)((base_kt + 1) * KVBLK + t * 16 + li) * C8 + lg * 8);

        char* pbase = (char*)&P_lds[0][wid][0][0];
#pragma unroll
        for (int r = 0; r < 4; r++) {
            float lp = 0.f;
            int row = lg * 4 + r;
            int swz = (row & 7) << 4;
#pragma unroll
            for (int t = 0; t < 4; t++) {
                float p = __builtin_amdgcn_exp2f(s[t][r] - SHIFT_L2);
                lp += p;
                int colb = (t * 16 + li) * 2;
                *(__bf16*)(pbase + row * (KVBLK * 2) + (colb ^ swz)) = (__bf16)p;
            }
            l_part[r] += lp;
        }
    }
    __syncthreads();

    int br = 0;                   // buffer holding tile i's P (read by PV)
    for (int i = 0; i < KT_PER; i++) {
        int m0 = (base_kt + i) * KVBLK;

        // ---- issue kk=0 V frags for tile i (consumed at PV below)
        bf16x8 vf0[4];
#pragma unroll
        for (int ct = 0; ct < 4; ct++)
            vf0[ct] = *(const bf16x8*)(Vbb
                + (size_t)(wid * 64 + ct * 16 + li) * N_DIM + m0 + lg * 8);

        // ---- pipeline stage for tile i+1: QK, K-prefetch(i+2), exp -> P[bw]
        if (i + 1 < KT_PER) {
            f32x4 s[4];
#pragma unroll
            for (int t = 0; t < 4; t++) {
                f32x4 z = {};
                s[t] = __builtin_amdgcn_mfma_f32_16x16x32_bf16(qf, kf[t], z, 0, 0, 0);
            }
            int i2 = (i + 2 < KT_PER) ? i + 2 : KT_PER - 1;
            int m0n = (base_kt + i2) * KVBLK;
#pragma unroll
            for (int t = 0; t < 4; t++)
                kf[t] = *(const bf16x8*)(Kb + (size_t)(m0n + t * 16 + li) * C8 + lg * 8);

            int bw = br + 1; if (bw == 3) bw = 0;
            char* pbase = (char*)&P_lds[bw][wid][0][0];
#pragma unroll
            for (int r = 0; r < 4; r++) {
                float lp = 0.f;
                int row = lg * 4 + r;
                int swz = (row & 7) << 4;
#pragma unroll
                for (int t = 0; t < 4; t++) {
                    float p = __builtin_amdgcn_exp2f(s[t][r] - SHIFT_L2);
                    lp += p;
                    int colb = (t * 16 + li) * 2;
                    *(__bf16*)(pbase + row * (KVBLK * 2) + (colb ^ swz)) = (__bf16)p;
                }
                l_part[r] += lp;
            }
        }

        // ---- PV(i): reads P_lds[br] (ready since last barrier) + vf0/vf1
        const char* prd = (const char*)&P_lds[br][0][0][0];
        const size_t quad = (size_t)16 * KVBLK * 2;   // bytes per wave-quadrant

        bf16x8 vf1[4];
#pragma unroll
        for (int ct = 0; ct < 4; ct++)
            vf1[ct] = *(const bf16x8*)(Vbb
                + (size_t)(wid * 64 + ct * 16 + li) * N_DIM + m0 + 32 + lg * 8);

        __builtin_amdgcn_s_setprio(1);
        {
            bf16x8 pf[4];
#pragma unroll
            for (int np = 0; np < 4; np++) {
                int row = li;
                int colb = lg * 16;
                pf[np] = *(const bf16x8*)(prd + np * quad
                                          + row * (KVBLK * 2) + (colb ^ ((row & 7) << 4)));
            }
#pragma unroll
            for (int ct = 0; ct < 4; ct++)
#pragma unroll
                for (int np = 0; np < 4; np++)
                    acc[ct][np] = __builtin_amdgcn_mfma_f32_16x16x32_bf16(vf0[ct], pf[np], acc[ct][np], 0, 0, 0);
        }
        {
            bf16x8 pf[4];
#pragma unroll
            for (int np = 0; np < 4; np++) {
                int row = li;
                int colb = 64 + lg * 16;
                pf[np] = *(const bf16x8*)(prd + np * quad
                                          + row * (KVBLK * 2) + (colb ^ ((row & 7) << 4)));
            }
#pragma unroll
            for (int ct = 0; ct < 4; ct++)
#pragma unroll
                for (int np = 0; np < 4; np++)
                    acc[ct][np] = __builtin_amdgcn_mfma_f32_16x16x32_bf16(vf1[ct], pf[np], acc[ct][np], 0, 0, 0);
        }
        __builtin_amdgcn_s_setprio(0);

        br++; if (br == 3) br = 0;
        __syncthreads();
    }

    // ---- epilogue: reduce l over the 16 li lanes (once), write partials
    size_t sb = (size_t)(sp * B_DIM + b);
#pragma unroll
    for (int r = 0; r < 4; r++) {
        float v = l_part[r];
        v += __shfl_xor(v, 1);
        v += __shfl_xor(v, 2);
        v += __shfl_xor(v, 4);
        v += __shfl_xor(v, 8);
        if (li == 0) {
            int q = n0 + wid * 16 + lg * 4 + r;
            Ll[sb * N_DIM + q] = v;
        }
    }
#pragma unroll
    for (int np = 0; np < 4; np++) {
#pragma unroll
        for (int ct = 0; ct < 4; ct++) {
#pragma unroll
            for (int r = 0; r < 4; r++) {
                int c = wid * 64 + ct * 16 + lg * 4 + r;
                int n = n0 + np * 16 + li;
                Op[(sb * C_DIM + c) * N_DIM + n] = (__bf16)acc[ct][np][r];
            }
        }
    }
}

// ---------------------------------------------------------------------------
// Kernel 3: combine (sum partials, one gamma/L multiply, residual)
// ---------------------------------------------------------------------------
__global__ __launch_bounds__(256) void k_combine(
    const float* __restrict__ x, const __bf16* __restrict__ Op,
    const float* __restrict__ Ll,
    const float* __restrict__ gamma, float* __restrict__ out)
{
    int tid = blockIdx.x * 256 + threadIdx.x;   // 131072 total
    int n4 = tid & 1023;
    int cg = (tid >> 10) & 15;
    int b  = tid >> 14;
    int n  = n4 * 4;
    float g = gamma[0];

    float inv[4];
    {
        float L[4] = {0.f, 0.f, 0.f, 0.f};
#pragma unroll
        for (int s = 0; s < SPLIT; s++) {
            float4 t1 = *(const float4*)(Ll + ((size_t)(s * B_DIM + b) << 12) + n);
            L[0] += t1.x; L[1] += t1.y; L[2] += t1.z; L[3] += t1.w;
        }
#pragma unroll
        for (int j = 0; j < 4; j++) inv[j] = g / L[j];
    }

#pragma unroll 4
    for (int ci = 0; ci < 16; ci++) {
        int c = cg * 16 + ci;
        size_t base = (((size_t)b * C_DIM + c) << 12) + n;
        float4 xv = *(const float4*)(x + base);
        float o0 = 0.f, o1 = 0.f, o2 = 0.f, o3 = 0.f;
#pragma unroll
        for (int s = 0; s < SPLIT; s++) {
            bf16x4 p = *(const bf16x4*)(Op + (((size_t)(s * B_DIM + b) * C_DIM + c) << 12) + n);
            o0 += (float)p[0];
            o1 += (float)p[1];
            o2 += (float)p[2];
            o3 += (float)p[3];
        }
        float4 ov = { xv.x + o0 * inv[0], xv.y + o1 * inv[1],
                      xv.z + o2 * inv[2], xv.w + o3 * inv[3] };
        *(float4*)(out + base) = ov;
    }
}

// ---------------------------------------------------------------------------
extern "C" void kernel_launch(void* const* d_in, const int* in_sizes, int n_in,
                              void* d_out, int out_size, void* d_ws, size_t ws_size,
                              hipStream_t stream)
{
    const float* x     = (const float*)d_in[0];
    const float* Wq    = (const float*)d_in[1];
    const float* bq    = (const float*)d_in[2];
    const float* Wk    = (const float*)d_in[3];
    const float* bk    = (const float*)d_in[4];
    const float* Wv    = (const float*)d_in[5];
    const float* bv    = (const float*)d_in[6];
    const float* gamma = (const float*)d_in[7];
    float* out = (float*)d_out;

    char* ws = (char*)d_ws;
    const size_t MB = 1024 * 1024;
    __bf16* xt = (__bf16*)ws;                      // 16 MiB
    __bf16* Qt = (__bf16*)(ws + 16 * MB);          //  2 MiB
    __bf16* Kt = (__bf16*)(ws + 18 * MB);          //  2 MiB
    __bf16* Vb = (__bf16*)(ws + 20 * MB);          // 16 MiB
    __bf16* Op = (__bf16*)(ws + 36 * MB);          // 32 MiB (2 splits x 16MB bf16)
    float*  Ll = (float*)(ws + 100 * MB);          // 256 KiB

    k_transpose<<<2048, 256, 0, stream>>>(x, xt);
    k_qkv<<<2560, 256, 0, stream>>>(Wq, bq, Wk, bk, Wv, bv, xt, Qt, Kt, Vb);
    k_attn<<<512 * SPLIT, 256, 0, stream>>>(Qt, Kt, Vb, Op, Ll);
    k_combine<<<512, 256, 0, stream>>>(x, Op, Ll, gamma, out);
}